// Round 11
// baseline (34.298 us; speedup 1.0000x reference)
//
#include <hip/hip_runtime.h>

typedef _Float16 f16x2 __attribute__((ext_vector_type(2)));
typedef _Float16 f16x8 __attribute__((ext_vector_type(8)));
typedef __fp16   fp16v2 __attribute__((ext_vector_type(2)));   // cvt_pkrtz return type
typedef float    f32x16 __attribute__((ext_vector_type(16)));
typedef unsigned int u32x4 __attribute__((ext_vector_type(4)));

#define TROWSTR 25   // T row stride in words: odd -> conflict-free scalar/read2 epilogue

__device__ __forceinline__ f16x2 pk2(float lo, float hi) {
    fp16v2 p = __builtin_amdgcn_cvt_pkrtz(lo, hi);
    return __builtin_bit_cast(f16x2, p);
}
__device__ __forceinline__ unsigned int pkbits(f16x2 a, f16x2 b) {
    f16x2 r = a * b;
    return __builtin_bit_cast(unsigned int, r);
}

// ---- single fused kernel: stage B in-block, 32x32x16 flattened-K GEMM, epilogue ----
// out[n] = sum_i sx_i * T[n,i], T[n,i] = sum_{j,k} sy_j sz_k C[i,j,k]
// Per wave: 64 points (2 M-tiles of 32). Lane: row mr=lane&31, k-half h=lane>>5.
// Step s (1..35), elem e: kk = 16s+8h+e; j=(2s+h)/3, k=8*((2s+h)%3)+e. (validated R10)
// B staged once per block into LDS (f16 frags, 35840 B); ONE ds_read_b128 per step.
// Native v_sin/v_cos take REVOLUTIONS: sin(2pi*x) = __builtin_amdgcn_sinf(x).
__global__ __launch_bounds__(256, 4) void fourier_fused(
    const float* __restrict__ xyz,
    const float* __restrict__ coeffs,
    float* __restrict__ out)
{
    __shared__ __align__(16) f16x8 Bl[2240];   // 35840 B; T overlay 4*64*25*4=25600 B

    const int tid  = threadIdx.x;
    const int wave = tid >> 6;
    const int lane = tid & 63;
    const int h    = lane >> 5;
    const int mr   = lane & 31;
    const bool hb  = (h != 0);

    const int p0 = (blockIdx.x * 4 + wave) * 64;

    // epilogue x preload (hide HBM latency behind staging + setup + loop)
    const float xv = xyz[3 * (p0 + lane)];

    // ---- stage B: 2240 chunks (s=1..35 x 64 lane-slots), each 8 f16 from C ----
#pragma unroll
    for (int pass = 0; pass < 9; ++pass) {
        int chunk = pass * 256 + tid;
        if (chunk < 2240) {
            int s = 1 + (chunk >> 6);        // 1..35
            int l = chunk & 63;
            int i = l & 31, hh = l >> 5;
            f16x8 v;
            if (i < 24) {
                const float* src = coeffs + i * 576 + 16 * s + 8 * hh;  // 32B-aligned
#pragma unroll
                for (int e = 0; e < 8; ++e) v[e] = (_Float16)src[e];
            } else {
#pragma unroll
                for (int e = 0; e < 8; ++e) v[e] = (_Float16)0.f;
            }
            Bl[chunk] = v;
        }
    }

    // ---- per-M-tile trig state (same math as R10, validated) ----
    float syp[2], syc[2], c2y[2];
    f16x2 szR[2][3][4];   // [mtile][rotated bank t][e-pair]; bank t holds k0=8*((t+h)%3)

#pragma unroll
    for (int mt = 0; mt < 2; ++mt) {
        int p = p0 + mt * 32 + mr;
        float y = xyz[3 * p + 1];
        float z = xyz[3 * p + 2];

        float s1y = __builtin_amdgcn_sinf(y);
        float c1y = __builtin_amdgcn_cosf(y);
        c2y[mt] = 2.f * c1y;
        // state (prev,cur) = (sy_{j-1}, sy_j) at s=1: j = h ? 1 : 0
        syc[mt] = hb ? s1y : 0.f;
        syp[mt] = hb ? 0.f : -s1y;

        float s1 = __builtin_amdgcn_sinf(z);
        float c1 = __builtin_amdgcn_cosf(z);
        float w8 = __builtin_amdgcn_fractf(8.f * z);
        float s8 = __builtin_amdgcn_sinf(w8);
        float c8 = __builtin_amdgcn_cosf(w8);
        float s16 = 2.f * s8 * c8;            // double angle
        float c16 = fmaf(2.f * c8, c8, -1.f);
        float c2z = 2.f * c1;

#pragma unroll
        for (int t = 0; t < 3; ++t) {
            float sk, ck;
            if (t == 0) { sk = hb ? s8  : 0.f;  ck = hb ? c8  : 1.f;  }
            if (t == 1) { sk = hb ? s16 : s8;   ck = hb ? c16 : c8;   }
            if (t == 2) { sk = hb ? 0.f : s16;  ck = hb ? 1.f : c16;  }
            float v[8];
            v[0] = sk;
            v[1] = fmaf(sk, c1, ck * s1);
#pragma unroll
            for (int e = 2; e < 8; ++e) v[e] = fmaf(c2z, v[e - 1], -v[e - 2]);
#pragma unroll
            for (int q = 0; q < 4; ++q) szR[mt][t][q] = pk2(v[2 * q], v[2 * q + 1]);
        }
    }

    f32x16 acc0 = {};
    f32x16 acc1 = {};

    __syncthreads();   // staging complete

    // ---- main loop: 1 ds_read_b128 + 2 MFMA per step ----
#pragma unroll
    for (int s = 1; s < 36; ++s) {
        f16x8 bs = Bl[(s - 1) * 64 + lane];   // imm-offset ds_read_b128, conflict-free
        const int t = (2 * s) % 3;            // compile-time rotated-bank index
        {
            f16x2 hy2 = pk2(syc[0], syc[0]);
            u32x4 aw;
            aw[0] = pkbits(hy2, szR[0][t][0]);
            aw[1] = pkbits(hy2, szR[0][t][1]);
            aw[2] = pkbits(hy2, szR[0][t][2]);
            aw[3] = pkbits(hy2, szR[0][t][3]);
            f16x8 a = __builtin_bit_cast(f16x8, aw);
            acc0 = __builtin_amdgcn_mfma_f32_32x32x16_f16(a, bs, acc0, 0, 0, 0);
        }
        {
            f16x2 hy2 = pk2(syc[1], syc[1]);
            u32x4 aw;
            aw[0] = pkbits(hy2, szR[1][t][0]);
            aw[1] = pkbits(hy2, szR[1][t][1]);
            aw[2] = pkbits(hy2, szR[1][t][2]);
            aw[3] = pkbits(hy2, szR[1][t][3]);
            f16x8 a = __builtin_bit_cast(f16x8, aw);
            acc1 = __builtin_amdgcn_mfma_f32_32x32x16_f16(a, bs, acc1, 0, 0, 0);
        }
        // advance sy: delta j = 0 iff (2s+h)%3 == 0
        if (s < 35) {
#pragma unroll
            for (int mt = 0; mt < 2; ++mt) {
                float t1 = fmaf(c2y[mt], syc[mt], -syp[mt]);
                if ((s % 3) == 2) {             // both halves advance
                    syp[mt] = syc[mt]; syc[mt] = t1;
                } else {
                    bool stay = ((s % 3) == 0) ? !hb : hb;
                    float np = stay ? syp[mt] : syc[mt];
                    float nc = stay ? syc[mt] : t1;
                    syp[mt] = np; syc[mt] = nc;
                }
            }
        }
    }

    __syncthreads();   // all waves done reading B -> overlay T

    // ---- scatter T (f32, wave-private): D row=(r&3)+8*(r>>2)+4h, col=mr ----
    float* Tw = (float*)Bl + wave * (64 * TROWSTR);
    if (mr < 24) {
#pragma unroll
        for (int r = 0; r < 16; ++r) {
            int row = (r & 3) + 8 * (r >> 2) + 4 * h;
            Tw[row * TROWSTR + mr]        = acc0[r];
            Tw[(32 + row) * TROWSTR + mr] = acc1[r];
        }
    }
    // T region wave-private: drain own LDS writes, no second barrier
    asm volatile("s_waitcnt lgkmcnt(0)" ::: "memory");

    // ---- epilogue: lane owns point row `lane`; stride-25 reads conflict-free ----
    {
        int p = p0 + lane;
        float s1 = __builtin_amdgcn_sinf(xv);
        float c1 = __builtin_amdgcn_cosf(xv);
        const float c2x = 2.f * c1;
        const float* Tr = Tw + lane * TROWSTR;
        float sp = 0.f, sc = s1, res = 0.f;
#pragma unroll
        for (int i = 1; i < 24; ++i) {
            res = fmaf(sc, Tr[i], res);
            float nx = fmaf(c2x, sc, -sp);
            sp = sc; sc = nx;
        }
        out[p] = res;
    }
}

extern "C" void kernel_launch(void* const* d_in, const int* in_sizes, int n_in,
                              void* d_out, int out_size, void* d_ws, size_t ws_size,
                              hipStream_t stream) {
    const float* xyz    = (const float*)d_in[0];
    const float* coeffs = (const float*)d_in[1];
    float* out = (float*)d_out;

    const int n = in_sizes[0] / 3;             // 524288 = 2048 blocks * 4 waves * 64
    const int grid = n / 256;
    fourier_fused<<<grid, 256, 0, stream>>>(xyz, coeffs, out);
}

// Round 12
// 32.082 us; speedup vs baseline: 1.0691x; 1.0691x over previous
//
#include <hip/hip_runtime.h>

typedef _Float16 f16x2 __attribute__((ext_vector_type(2)));
typedef _Float16 f16x8 __attribute__((ext_vector_type(8)));
typedef __fp16   fp16v2 __attribute__((ext_vector_type(2)));   // cvt_pkrtz return type
typedef float    f32x16 __attribute__((ext_vector_type(16)));
typedef unsigned int u32x4 __attribute__((ext_vector_type(4)));

#define TROWSTR 25   // T row stride in words (coprime 32 -> conflict-free epilogue)

__device__ __forceinline__ f16x2 pk2(float lo, float hi) {
    fp16v2 p = __builtin_amdgcn_cvt_pkrtz(lo, hi);
    return __builtin_bit_cast(f16x2, p);
}
__device__ __forceinline__ unsigned int pkbits(f16x2 a, f16x2 b) {
    f16x2 r = a * b;
    return __builtin_bit_cast(unsigned int, r);
}

// ---- prep: C (f32) -> flattened-K f16 B table (validated R10) ----
// wsB[s*64 + l][e] = f16(C[i][kk]), i = l&31 (0 if i>=24), kk = 16s + 8*(l>>5) + e
__global__ __launch_bounds__(256) void prep_B(const float* __restrict__ coeffs,
                                              f16x8* __restrict__ wsB)
{
    int chunk = blockIdx.x * 256 + threadIdx.x;   // 0..2303 = 36 steps * 64 lanes
    int s = chunk >> 6, l = chunk & 63;
    int i = l & 31, h = l >> 5;
    f16x8 v;
    if (i < 24) {
        const float* src = coeffs + i * 576 + 16 * s + 8 * h;
#pragma unroll
        for (int e = 0; e < 8; ++e) v[e] = (_Float16)src[e];
    } else {
#pragma unroll
        for (int e = 0; e < 8; ++e) v[e] = (_Float16)0.f;
    }
    wsB[chunk] = v;
}

// ---- main: ONE-ROUND persistent waves. 2048 waves total (2/SIMD, all resident).
// Each wave: 256 points = 8 outer iterations of one 32x32 M-tile.
// Persistent B (35 frags, 140 VGPR) loaded once; flattened K (validated R10):
// step s (1..35), elem e: kk = 16s+8h+e; j=(2s+h)/3, k=8*((2s+h)%3)+e.
// Native v_sin/v_cos take REVOLUTIONS: sin(2pi*x) = __builtin_amdgcn_sinf(x).
__global__ __launch_bounds__(256, 2) void fourier_main(
    const float* __restrict__ xyz,
    const f16x8* __restrict__ wsB,
    float* __restrict__ out)
{
    __shared__ __align__(16) float Tl[4 * 32 * TROWSTR];   // 12800 B, wave-private rows

    const int tid  = threadIdx.x;
    const int wave = tid >> 6;
    const int lane = tid & 63;
    const int h    = lane >> 5;
    const int mr   = lane & 31;
    const bool hb  = (h != 0);

    const int pw = (blockIdx.x * 4 + wave) * 256;   // wave's 256 points

    // ---- persistent B: 35 fragments in registers ----
    f16x8 bt[36];
#pragma unroll
    for (int s = 1; s < 36; ++s) bt[s] = wsB[s * 64 + lane];

    // initial point loads (iter 0); both halves load the same point row mr
    float cx = xyz[3 * (pw + mr) + 0];
    float cy = xyz[3 * (pw + mr) + 1];
    float cz = xyz[3 * (pw + mr) + 2];

    float* Tw = Tl + wave * (32 * TROWSTR);

#pragma unroll 1
    for (int it = 0; it < 8; ++it) {
        const int pp0 = pw + it * 32;

        // prefetch next iteration's point EARLY (hides HBM under trig+MFMA)
        int pn = (it < 7) ? (pp0 + 32 + mr) : (pw + mr);
        float nx = xyz[3 * pn + 0];
        float ny = xyz[3 * pn + 1];
        float nz = xyz[3 * pn + 2];

        // ---- trig setup (R10 math, single M-tile) ----
        float s1y = __builtin_amdgcn_sinf(cy);
        float c1y = __builtin_amdgcn_cosf(cy);
        float c2y = 2.f * c1y;
        // state (prev,cur) = (sy_{j-1}, sy_j) at s=1: j = h ? 1 : 0
        float syc = hb ? s1y : 0.f;
        float syp = hb ? 0.f : -s1y;

        float s1 = __builtin_amdgcn_sinf(cz);
        float c1 = __builtin_amdgcn_cosf(cz);
        float w8 = __builtin_amdgcn_fractf(8.f * cz);
        float s8 = __builtin_amdgcn_sinf(w8);
        float c8 = __builtin_amdgcn_cosf(w8);
        float s16 = 2.f * s8 * c8;            // double angle
        float c16 = fmaf(2.f * c8, c8, -1.f);
        float c2z = 2.f * c1;

        f16x2 szR[3][4];   // rotated bank t holds k0 = 8*((t+h)%3)
#pragma unroll
        for (int t = 0; t < 3; ++t) {
            float sk, ck;
            if (t == 0) { sk = hb ? s8  : 0.f;  ck = hb ? c8  : 1.f;  }
            if (t == 1) { sk = hb ? s16 : s8;   ck = hb ? c16 : c8;   }
            if (t == 2) { sk = hb ? 0.f : s16;  ck = hb ? 1.f : c16;  }
            float v[8];
            v[0] = sk;
            v[1] = fmaf(sk, c1, ck * s1);
#pragma unroll
            for (int e = 2; e < 8; ++e) v[e] = fmaf(c2z, v[e - 1], -v[e - 2]);
#pragma unroll
            for (int q = 0; q < 4; ++q) szR[t][q] = pk2(v[2 * q], v[2 * q + 1]);
        }

        f32x16 acc = {};

        // ---- main loop: pure VALU + MFMA, no memory ops ----
#pragma unroll
        for (int s = 1; s < 36; ++s) {
            const int t = (2 * s) % 3;        // compile-time rotated-bank index
            f16x2 hy2 = pk2(syc, syc);
            u32x4 aw;
            aw[0] = pkbits(hy2, szR[t][0]);
            aw[1] = pkbits(hy2, szR[t][1]);
            aw[2] = pkbits(hy2, szR[t][2]);
            aw[3] = pkbits(hy2, szR[t][3]);
            f16x8 a = __builtin_bit_cast(f16x8, aw);
            acc = __builtin_amdgcn_mfma_f32_32x32x16_f16(a, bt[s], acc, 0, 0, 0);
            // advance sy: delta j = 0 iff (2s+h)%3 == 0
            if (s < 35) {
                float t1 = fmaf(c2y, syc, -syp);
                if ((s % 3) == 2) {           // both halves advance
                    syp = syc; syc = t1;
                } else {
                    bool stay = ((s % 3) == 0) ? !hb : hb;
                    float np = stay ? syp : syc;
                    float nc = stay ? syc : t1;
                    syp = np; syc = nc;
                }
            }
        }

        // ---- scatter T (wave-private): D row=(r&3)+8*(r>>2)+4h, col=mr ----
        if (mr < 24) {
#pragma unroll
            for (int r = 0; r < 16; ++r) {
                int row = (r & 3) + 8 * (r >> 2) + 4 * h;
                Tw[row * TROWSTR + mr] = acc[r];
            }
        }
        asm volatile("s_waitcnt lgkmcnt(0)" ::: "memory");   // wave-local drain

        // ---- epilogue: both halves compute row mr; lanes<32 store ----
        {
            float sx1 = __builtin_amdgcn_sinf(cx);
            float cx1 = __builtin_amdgcn_cosf(cx);
            const float c2x = 2.f * cx1;
            const float* Tr = Tw + mr * TROWSTR;
            float sp = 0.f, sc = sx1, res = 0.f;
#pragma unroll
            for (int i = 1; i < 24; ++i) {
                res = fmaf(sc, Tr[i], res);
                float nxr = fmaf(c2x, sc, -sp);
                sp = sc; sc = nxr;
            }
            if (lane < 32) out[pp0 + mr] = res;
        }

        cx = nx; cy = ny; cz = nz;
    }
}

extern "C" void kernel_launch(void* const* d_in, const int* in_sizes, int n_in,
                              void* d_out, int out_size, void* d_ws, size_t ws_size,
                              hipStream_t stream) {
    const float* xyz    = (const float*)d_in[0];
    const float* coeffs = (const float*)d_in[1];
    float* out = (float*)d_out;
    f16x8* wsB = (f16x8*)d_ws;                 // needs 36864 B

    prep_B<<<9, 256, 0, stream>>>(coeffs, wsB);

    const int n = in_sizes[0] / 3;             // 524288 = 512 blocks * 4 waves * 256
    const int grid = n / 1024;
    fourier_main<<<grid, 256, 0, stream>>>(xyz, wsB, out);
}